// Round 1
// baseline (7089.414 us; speedup 1.0000x reference)
//
#include <hip/hip_runtime.h>
#include <hip/hip_bf16.h>
#include <hip/hip_fp8.h>
#include <cstdint>
#include <cstddef>

// VanillaRNN: h_{t+1} = tanh(x_t @ Whx + h_t @ Whh + bh), p = h_T @ Wph + bp
// B=256, T=1024, D=64, H=512, C=10.
//
// Design (zero inter-block sync):
//  - 16 blocks x 256 threads (4 waves), one block per 16 batch rows, persistent
//    over all 1024 steps. Batch rows are independent -> no cross-block traffic.
//  - GEMM per step: C[16x512] += A[16x576] * W[576x512], K = [x(64)|h(512)],
//    via mfma_f32_16x16x32_bf16. Per-CU floor: 144 MFMA/wave * 16cyc = 2304 cyc.
//  - Weights resident per CU (streaming from L2 would be ~2.4x MFMA time):
//    wave w owns cols [w*128,w*128+128): 96 frags (k<384) in VGPRs as bf16
//    (384 VGPRs), 48 frags (k in [384,576)) in LDS as fp8-e4m3 scaled by 256,
//    decoded to bf16 each step (co-issues with MFMA).
//  - h ping-pong in LDS (A-concat buffer, +8 bf16 pad -> 2-way bank alias, free).
//    ONE __syncthreads per step. x_{t+1} loaded at step top (latency hidden).
//  - LDS total 135,680 B (needs >64KB opt-in); VGPR ~460 @ 1 wave/SIMD.

#define T_SEQ   1024
#define D_IN    64
#define H_DIM   512
#define KTOT    576
#define NB      16          // batch rows per block
#define NBLK    16          // blocks
#define PITCH   584         // KTOT + 8 bf16 pad
#define NKS     18          // K-steps of 32
#define RKS     12          // K-steps with register-resident weights
#define LKS     6           // K-steps with LDS fp8 weights
#define RFRAGS  (RKS*8)     // 96
#define LFRAGS  (LKS*8)     // 48
#define FP8_SCALE 256.0f
#define FP8_INV   (1.0f/256.0f)

#define SMEM_ABUF (2 * NB * PITCH * 2)            // 37376 B
#define SMEM_W    (4 * LFRAGS * 512)              // 98304 B
#define SMEM_TOTAL (SMEM_ABUF + SMEM_W)           // 135680 B

typedef __attribute__((ext_vector_type(8))) short  short8;
typedef __attribute__((ext_vector_type(4))) short  short4v;
typedef __attribute__((ext_vector_type(4))) float  f32x4;
typedef __attribute__((ext_vector_type(2))) float  f32x2;
typedef __attribute__((ext_vector_type(4))) unsigned int uint4v;

__device__ __forceinline__ short bf16b(float v) {
  __hip_bfloat16 h = __float2bfloat16(v);
  return __builtin_bit_cast(short, h);
}

__device__ __forceinline__ float fp8_to_f32_slow(unsigned int byte) {
  __hip_fp8_e4m3 f;
  f.__x = (__hip_fp8_storage_t)byte;
  return (float)f;
}

// 8 fp8 bytes (lo: j0..3, hi: j4..7) -> 8 bf16, unscaling by 1/256
__device__ __forceinline__ short8 dec8(unsigned int lo, unsigned int hi) {
  short8 r;
#if defined(__has_builtin) && __has_builtin(__builtin_amdgcn_cvt_pk_f32_fp8)
  f32x2 p0 = __builtin_amdgcn_cvt_pk_f32_fp8(lo, false);
  f32x2 p1 = __builtin_amdgcn_cvt_pk_f32_fp8(lo, true);
  f32x2 p2 = __builtin_amdgcn_cvt_pk_f32_fp8(hi, false);
  f32x2 p3 = __builtin_amdgcn_cvt_pk_f32_fp8(hi, true);
  r[0] = bf16b(p0.x * FP8_INV); r[1] = bf16b(p0.y * FP8_INV);
  r[2] = bf16b(p1.x * FP8_INV); r[3] = bf16b(p1.y * FP8_INV);
  r[4] = bf16b(p2.x * FP8_INV); r[5] = bf16b(p2.y * FP8_INV);
  r[6] = bf16b(p3.x * FP8_INV); r[7] = bf16b(p3.y * FP8_INV);
#else
  #pragma unroll
  for (int i = 0; i < 4; ++i)
    r[i]     = bf16b(fp8_to_f32_slow((lo >> (8*i)) & 0xffu) * FP8_INV);
  #pragma unroll
  for (int i = 0; i < 4; ++i)
    r[4 + i] = bf16b(fp8_to_f32_slow((hi >> (8*i)) & 0xffu) * FP8_INV);
#endif
  return r;
}

__global__ __launch_bounds__(256, 1)
void VanillaRNN_70025146794452_kernel(
    const float* __restrict__ x,    // [256][1024][64]
    const float* __restrict__ Whx,  // [64][512]
    const float* __restrict__ Whh,  // [512][512]
    const float* __restrict__ Wph,  // [512][10]
    const float* __restrict__ bh,   // [512]
    const float* __restrict__ bp,   // [10]
    float* __restrict__ out)        // [256][10]
{
  const int tid   = threadIdx.x;
  const int lane  = tid & 63;
  const int w     = tid >> 6;       // wave 0..3
  const int n16   = lane & 15;      // MFMA row/col-within-tile
  const int kq    = lane >> 4;      // MFMA quad
  const int rbase = blockIdx.x * NB;
  const int cwave = w * 128;

  extern __shared__ char smem[];
  short* Ab = (short*)smem;                               // [2][NB][PITCH] bf16
  unsigned char* Wl  = (unsigned char*)(smem + SMEM_ABUF);
  unsigned char* Wlw = Wl + w * (LFRAGS * 512);           // this wave's fp8 region

  // ---------------- preload: register-resident bf16 B-fragments ----------------
  // B-frag layout for 16x16x32: lane holds B[k0 + kq*8 + j][c0 + n16], j=0..7
  short8 wr[RFRAGS];
  #pragma unroll
  for (int s = 0; s < RKS; ++s) {
    #pragma unroll
    for (int nt = 0; nt < 8; ++nt) {
      const int c  = cwave + nt * 16 + n16;
      const int k0 = s * 32 + kq * 8;
      short8 f;
      #pragma unroll
      for (int j = 0; j < 8; ++j) {
        const int k = k0 + j;
        const float* src = (k < D_IN) ? (Whx + (size_t)k * H_DIM + c)
                                      : (Whh + (size_t)(k - D_IN) * H_DIM + c);
        f[j] = bf16b(*src);
      }
      wr[s * 8 + nt] = f;
    }
  }

  // ---------------- preload: LDS fp8 B-fragments (stored as frag PAIRS) -------
  // pair p = (s*4+pp) covers nt=2pp,2pp+1; lane stores 16B at p*1024 + lane*16.
  for (int s = 0; s < LKS; ++s) {
    for (int pp = 0; pp < 4; ++pp) {
      const int k0 = (RKS + s) * 32 + kq * 8;   // >= 384, always in Whh
      unsigned int b[4];
      #pragma unroll
      for (int half = 0; half < 2; ++half) {
        const int c = cwave + (2 * pp + half) * 16 + n16;
        #pragma unroll
        for (int u = 0; u < 2; ++u) {
          unsigned int acc = 0;
          #pragma unroll
          for (int bi = 0; bi < 4; ++bi) {
            const int k = k0 + u * 4 + bi;
            float v = Whh[(size_t)(k - D_IN) * H_DIM + c] * FP8_SCALE;
            __hip_fp8_e4m3 f8(v);
            acc |= ((unsigned int)f8.__x) << (8 * bi);
          }
          b[half * 2 + u] = acc;
        }
      }
      uint4v pk; pk.x = b[0]; pk.y = b[1]; pk.z = b[2]; pk.w = b[3];
      *(uint4v*)(Wlw + (size_t)(s * 4 + pp) * 1024 + lane * 16) = pk;
    }
  }

  // bias registers (one per N-tile, per lane's column)
  float bhreg[8];
  #pragma unroll
  for (int nt = 0; nt < 8; ++nt) bhreg[nt] = bh[cwave + nt * 16 + n16];

  // ---------------- prologue: h_0 = 0, x_0 into Abuf[0] ----------------
  for (int i = tid; i < NB * H_DIM; i += 256) {
    const int r = i >> 9, c = i & 511;
    Ab[r * PITCH + D_IN + c] = 0;
  }
  {
    const int r = tid >> 4, c4 = (tid & 15) * 4;
    const f32x4 xv = *(const f32x4*)(x + ((size_t)(rbase + r) * T_SEQ + 0) * D_IN + c4);
    short4v s4; s4[0] = bf16b(xv.x); s4[1] = bf16b(xv.y);
    s4[2] = bf16b(xv.z); s4[3] = bf16b(xv.w);
    *(short4v*)(Ab + r * PITCH + c4) = s4;
  }

  f32x4 C[8];
  const int xr = tid >> 4, xc4 = (tid & 15) * 4;

  // ---------------- main recurrence ----------------
  for (int t = 0; t < T_SEQ; ++t) {
    __syncthreads();   // Abuf[t&1] fully written (h_t + x_t)
    const short* Ac = Ab + (t & 1) * (NB * PITCH);
    short*       An = Ab + ((t + 1) & 1) * (NB * PITCH);

    // issue x_{t+1} load early (consumed after MFMA phase)
    const int t1 = (t + 1 < T_SEQ) ? (t + 1) : (T_SEQ - 1);
    const f32x4 xv = *(const f32x4*)(x + ((size_t)(rbase + xr) * T_SEQ + t1) * D_IN + xc4);

    #pragma unroll
    for (int nt = 0; nt < 8; ++nt) C[nt] = (f32x4){0.f, 0.f, 0.f, 0.f};

    // register-weight K-steps: A-frag = Ac[m=n16][k0 + kq*8 .. +8]
    #pragma unroll
    for (int s = 0; s < RKS; ++s) {
      const short8 a = *(const short8*)(Ac + n16 * PITCH + s * 32 + kq * 8);
      #pragma unroll
      for (int nt = 0; nt < 8; ++nt)
        C[nt] = __builtin_amdgcn_mfma_f32_16x16x32_bf16(a, wr[s * 8 + nt], C[nt], 0, 0, 0);
    }
    // LDS fp8-weight K-steps
    #pragma unroll
    for (int s = 0; s < LKS; ++s) {
      const short8 a = *(const short8*)(Ac + n16 * PITCH + (RKS + s) * 32 + kq * 8);
      #pragma unroll
      for (int pp = 0; pp < 4; ++pp) {
        const uint4v q = *(const uint4v*)(Wlw + (size_t)(s * 4 + pp) * 1024 + lane * 16);
        const short8 b0 = dec8(q.x, q.y);
        const short8 b1 = dec8(q.z, q.w);
        C[2 * pp]     = __builtin_amdgcn_mfma_f32_16x16x32_bf16(a, b0, C[2 * pp],     0, 0, 0);
        C[2 * pp + 1] = __builtin_amdgcn_mfma_f32_16x16x32_bf16(a, b1, C[2 * pp + 1], 0, 0, 0);
      }
    }

    // stage x_{t+1} into next buffer
    {
      short4v s4; s4[0] = bf16b(xv.x); s4[1] = bf16b(xv.y);
      s4[2] = bf16b(xv.z); s4[3] = bf16b(xv.w);
      *(short4v*)(An + xr * PITCH + xc4) = s4;
    }

    // epilogue: h_{t+1} = tanh(C + bh) -> next buffer (C/D: row = kq*4+i, col = n16)
    const int row0 = kq * 4;
    #pragma unroll
    for (int nt = 0; nt < 8; ++nt) {
      const int c = D_IN + cwave + nt * 16 + n16;
      #pragma unroll
      for (int i = 0; i < 4; ++i) {
        const float v = tanhf(C[nt][i] + bhreg[nt]);
        An[(row0 + i) * PITCH + c] = bf16b(v);
      }
    }
  }

  __syncthreads();
  // final h_1024 lives in Abuf[0]. Projection: 16 rows x 10 classes per block.
  if (tid < NB * 10) {
    const int r = tid / 10, c = tid % 10;
    float acc = bp[c];
    #pragma unroll 8
    for (int k = 0; k < H_DIM; ++k) {
      const __hip_bfloat16 hb = __builtin_bit_cast(__hip_bfloat16, Ab[r * PITCH + D_IN + k]);
      acc += __bfloat162float(hb) * Wph[k * 10 + c];
    }
    out[(size_t)(rbase + r) * 10 + c] = acc;
  }
}

extern "C" void kernel_launch(void* const* d_in, const int* in_sizes, int n_in,
                              void* d_out, int out_size, void* d_ws, size_t ws_size,
                              hipStream_t stream) {
  const float* x   = (const float*)d_in[0];
  const float* Whx = (const float*)d_in[1];
  const float* Whh = (const float*)d_in[2];
  const float* Wph = (const float*)d_in[3];
  const float* bh  = (const float*)d_in[4];
  const float* bp  = (const float*)d_in[5];
  float* out = (float*)d_out;

  // opt-in to >64KB dynamic LDS (idempotent; no stream interaction)
  (void)hipFuncSetAttribute((const void*)VanillaRNN_70025146794452_kernel,
                            hipFuncAttributeMaxDynamicSharedMemorySize, SMEM_TOTAL);

  VanillaRNN_70025146794452_kernel<<<dim3(NBLK), dim3(256), SMEM_TOTAL, stream>>>(
      x, Whx, Whh, Wph, bh, bp, out);
}

// Round 2
// 4644.255 us; speedup vs baseline: 1.5265x; 1.5265x over previous
//
#include <hip/hip_runtime.h>
#include <hip/hip_bf16.h>
#include <hip/hip_fp8.h>
#include <cstdint>
#include <cstddef>

// VanillaRNN: h_{t+1} = tanh(x_t @ Whx + h_t @ Whh + bh), p = h_T @ Wph + bp
// B=256, T=1024, D=64, H=512, C=10.
//
// R1 changes vs R0 (R0: 7089us, per-active-CU VALUBusy 42% / MfmaUtil 14% ->
// VALU-bound on fp8 decode + libm tanhf):
//  - LDS weight slice (k in [384,576)) now feeds mfma_f32_16x16x32_fp8_fp8
//    DIRECTLY (no fp8->bf16 decode, -~960 VALU inst/step/wave). Matching h
//    slice (cols 320..512) is stored in the A-buffer as fp8 e4m3 (x128, HW
//    cvt_pk_fp8_f32); separate accumulator C2 rescaled by 2^-15 at epilogue.
//  - tanhf -> exp2-based fast tanh (~6 VALU vs ~30).
//  - A-row pitch 1040 B (=4 dwords mod 32 banks) for frag-read bank spread.
// Unchanged: 16 blocks x 4 waves (zero inter-block sync), wave owns 128 cols,
// k<384 weights bf16 in VGPR/AGPR (384 regs), h ping-pong in LDS, 1 barrier/step.

#define T_SEQ   1024
#define D_IN    64
#define H_DIM   512
#define NB      16
#define NBLK    16
#define RKS     12          // bf16 K-steps: k in [0,384) -> x(64) + h[0,320)
#define LKS     6           // fp8  K-steps: k in [384,576) -> h[320,512)
#define APITCH  1040        // bytes per A row: 768 bf16 + 192 fp8 + pad
#define FP8OFF  768         // byte offset of fp8 region (k=384) within a row
#define HSPLIT  320         // h columns >= HSPLIT stored as fp8
#define ABUF_BYTES (2 * NB * APITCH)             // 33280
#define WLDS_BYTES (4 * LKS * 4 * 1024)          // 98304
#define SMEM_TOTAL (ABUF_BYTES + WLDS_BYTES)     // 131584
#define WSCALE  256.0f      // fp8 weight pre-scale
#define HSCALE  128.0f      // fp8 h pre-scale
#define UNSCALE (1.0f / 32768.0f)                // 2^-15 = 1/(WSCALE*HSCALE)

typedef __attribute__((ext_vector_type(8))) short  short8;
typedef __attribute__((ext_vector_type(4))) short  short4v;
typedef __attribute__((ext_vector_type(4))) float  f32x4;
typedef __attribute__((ext_vector_type(4))) unsigned int uint4v;

static __device__ __forceinline__ short bf16b(float v) {
  return __builtin_bit_cast(short, __float2bfloat16(v));
}

static __device__ __forceinline__ float fast_tanh(float x) {
  // (e^2x - 1)/(e^2x + 1); clamp keeps exp2 finite (pre-act is O(1) anyway)
  x = fminf(20.f, fmaxf(-20.f, x));
  const float t = __builtin_amdgcn_exp2f(x * 2.885390081777927f); // 2*log2(e)
  return (t - 1.f) * __builtin_amdgcn_rcpf(t + 1.f);
}

static __device__ __forceinline__ unsigned char f32_to_fp8(float v) {
#if defined(__has_builtin) && __has_builtin(__builtin_amdgcn_cvt_pk_fp8_f32)
  const int r = __builtin_amdgcn_cvt_pk_fp8_f32(v, v, 0, false);
  return (unsigned char)(r & 0xff);
#else
  __hip_fp8_e4m3 f(v);
  return (unsigned char)f.__x;
#endif
}

static __device__ __forceinline__ float fp8_to_f32(unsigned char b) {
  __hip_fp8_e4m3 f;
  f.__x = (__hip_fp8_storage_t)b;
  return (float)f;
}

__global__ __launch_bounds__(256, 1)
void VanillaRNN_70025146794452_kernel(
    const float* __restrict__ x,    // [256][1024][64]
    const float* __restrict__ Whx,  // [64][512]
    const float* __restrict__ Whh,  // [512][512]
    const float* __restrict__ Wph,  // [512][10]
    const float* __restrict__ bh,   // [512]
    const float* __restrict__ bp,   // [10]
    float* __restrict__ out)        // [256][10]
{
  const int tid   = threadIdx.x;
  const int lane  = tid & 63;
  const int w     = tid >> 6;
  const int n16   = lane & 15;
  const int kq    = lane >> 4;
  const int rbase = blockIdx.x * NB;
  const int cwave = w * 128;

  extern __shared__ char smem[];
  char* Ab  = smem;                          // [2][NB][APITCH]
  char* Wlw = smem + ABUF_BYTES + w * (LKS * 4 * 1024);

  // ---------------- preload: register-resident bf16 B-fragments (k<384) -------
  // 16x16x32 B-frag: lane holds B[k0 + kq*8 + j][c0 + n16], j=0..7
  short8 wr[RKS * 8];
  #pragma unroll
  for (int s = 0; s < RKS; ++s) {
    #pragma unroll
    for (int nt = 0; nt < 8; ++nt) {
      const int c  = cwave + nt * 16 + n16;
      const int k0 = s * 32 + kq * 8;
      short8 f;
      #pragma unroll
      for (int j = 0; j < 8; ++j) {
        const int k = k0 + j;
        const float* src = (k < D_IN) ? (Whx + (size_t)k * H_DIM + c)
                                      : (Whh + (size_t)(k - D_IN) * H_DIM + c);
        f[j] = bf16b(*src);
      }
      wr[s * 8 + nt] = f;
    }
  }

  // ---------------- preload: LDS fp8 B-fragments (k in [384,576)) -------------
  // fp8 frag = 8 bytes/lane (k-consecutive). Pair p=s*4+pp holds nt=2pp (bytes
  // 0..7 -> q.x,q.y) and nt=2pp+1 (bytes 8..15 -> q.z,q.w) at p*1024 + lane*16.
  for (int s = 0; s < LKS; ++s) {
    for (int pp = 0; pp < 4; ++pp) {
      const int k0 = (RKS + s) * 32 + kq * 8;   // >= 384 -> Whh row k0-64 >= 320
      unsigned int b[4];
      #pragma unroll
      for (int half = 0; half < 2; ++half) {
        const int c = cwave + (2 * pp + half) * 16 + n16;
        #pragma unroll
        for (int u = 0; u < 2; ++u) {
          unsigned int acc = 0;
          #pragma unroll
          for (int bi = 0; bi < 4; ++bi) {
            const int k = k0 + u * 4 + bi;
            acc |= ((unsigned int)f32_to_fp8(Whh[(size_t)(k - D_IN) * H_DIM + c] * WSCALE))
                   << (8 * bi);
          }
          b[half * 2 + u] = acc;
        }
      }
      uint4v pk; pk.x = b[0]; pk.y = b[1]; pk.z = b[2]; pk.w = b[3];
      *(uint4v*)(Wlw + (size_t)(s * 4 + pp) * 1024 + lane * 16) = pk;
    }
  }

  float bhreg[8];
  #pragma unroll
  for (int nt = 0; nt < 8; ++nt) bhreg[nt] = bh[cwave + nt * 16 + n16];

  // ---------------- prologue: zero both A buffers, stage x_0 ------------------
  for (int i = tid; i < ABUF_BYTES / 4; i += 256) ((int*)Ab)[i] = 0;
  const int xr = tid >> 4, xc4 = (tid & 15) * 4;
  {
    const f32x4 xv = *(const f32x4*)(x + ((size_t)(rbase + xr) * T_SEQ + 0) * D_IN + xc4);
    short4v s4; s4[0] = bf16b(xv.x); s4[1] = bf16b(xv.y);
    s4[2] = bf16b(xv.z); s4[3] = bf16b(xv.w);
    *(short4v*)(Ab + xr * APITCH + xc4 * 2) = s4;
  }

  f32x4 C[8], C2[8];

  // ---------------- main recurrence ----------------
  for (int t = 0; t < T_SEQ; ++t) {
    __syncthreads();
    char* Ac = Ab + (t & 1) * (NB * APITCH);
    char* An = Ab + ((t + 1) & 1) * (NB * APITCH);

    const int t1 = (t + 1 < T_SEQ) ? (t + 1) : (T_SEQ - 1);
    const f32x4 xv = *(const f32x4*)(x + ((size_t)(rbase + xr) * T_SEQ + t1) * D_IN + xc4);

    #pragma unroll
    for (int nt = 0; nt < 8; ++nt) {
      C[nt]  = (f32x4){0.f, 0.f, 0.f, 0.f};
      C2[nt] = (f32x4){0.f, 0.f, 0.f, 0.f};
    }

    // bf16 section: k in [0,384), weights in registers
    #pragma unroll
    for (int s = 0; s < RKS; ++s) {
      const short8 a = *(const short8*)(Ac + n16 * APITCH + s * 64 + kq * 16);
      #pragma unroll
      for (int nt = 0; nt < 8; ++nt)
        C[nt] = __builtin_amdgcn_mfma_f32_16x16x32_bf16(a, wr[s * 8 + nt], C[nt], 0, 0, 0);
    }

    // fp8 section: k in [384,576), weights in LDS, A slice fp8 — no decode
    #pragma unroll
    for (int s = 0; s < LKS; ++s) {
      const long long a8 = *(const long long*)(Ac + n16 * APITCH + FP8OFF + s * 32 + kq * 8);
      #pragma unroll
      for (int pp = 0; pp < 4; ++pp) {
        const uint4v q = *(const uint4v*)(Wlw + (size_t)(s * 4 + pp) * 1024 + lane * 16);
        const long long b0 = (long long)(((unsigned long long)q.y << 32) | q.x);
        const long long b1 = (long long)(((unsigned long long)q.w << 32) | q.z);
        C2[2 * pp]     = __builtin_amdgcn_mfma_f32_16x16x32_fp8_fp8(a8, b0, C2[2 * pp],     0, 0, 0);
        C2[2 * pp + 1] = __builtin_amdgcn_mfma_f32_16x16x32_fp8_fp8(a8, b1, C2[2 * pp + 1], 0, 0, 0);
      }
    }

    // stage x_{t+1}
    {
      short4v s4; s4[0] = bf16b(xv.x); s4[1] = bf16b(xv.y);
      s4[2] = bf16b(xv.z); s4[3] = bf16b(xv.w);
      *(short4v*)(An + xr * APITCH + xc4 * 2) = s4;
    }

    // epilogue: h = tanh(C + C2*2^-15 + bh); C/D row = kq*4+i, col = n16
    const int row0 = kq * 4;
    #pragma unroll
    for (int nt = 0; nt < 8; ++nt) {
      const int cbase = cwave + nt * 16;       // wave-uniform; split at 320 is x16
      #pragma unroll
      for (int i = 0; i < 4; ++i) {
        const float v = fast_tanh(fmaf(C2[nt][i], UNSCALE, C[nt][i]) + bhreg[nt]);
        char* dst = An + (row0 + i) * APITCH;
        if (cbase < HSPLIT) {
          *(short*)(dst + 128 + (cbase + n16) * 2) = bf16b(v);
        } else {
          dst[FP8OFF + (cbase + n16 - HSPLIT)] = f32_to_fp8(v * HSCALE);
        }
      }
    }
  }

  __syncthreads();
  // h_T is in buffer 0 (T even). Projection: 16 rows x 10 classes per block.
  if (tid < NB * 10) {
    const int r = tid / 10, c = tid % 10;
    const char* row = Ab + r * APITCH;
    float acc = bp[c];
    #pragma unroll 8
    for (int k = 0; k < HSPLIT; ++k) {
      const __hip_bfloat16 hb = __builtin_bit_cast(__hip_bfloat16, *(const short*)(row + 128 + k * 2));
      acc += __bfloat162float(hb) * Wph[k * 10 + c];
    }
    #pragma unroll 8
    for (int k = HSPLIT; k < H_DIM; ++k) {
      acc += fp8_to_f32((unsigned char)row[FP8OFF + (k - HSPLIT)]) * (1.f / HSCALE) * Wph[k * 10 + c];
    }
    out[(size_t)(rbase + r) * 10 + c] = acc;
  }
}

extern "C" void kernel_launch(void* const* d_in, const int* in_sizes, int n_in,
                              void* d_out, int out_size, void* d_ws, size_t ws_size,
                              hipStream_t stream) {
  const float* x   = (const float*)d_in[0];
  const float* Whx = (const float*)d_in[1];
  const float* Whh = (const float*)d_in[2];
  const float* Wph = (const float*)d_in[3];
  const float* bh  = (const float*)d_in[4];
  const float* bp  = (const float*)d_in[5];
  float* out = (float*)d_out;

  (void)hipFuncSetAttribute((const void*)VanillaRNN_70025146794452_kernel,
                            hipFuncAttributeMaxDynamicSharedMemorySize, SMEM_TOTAL);

  VanillaRNN_70025146794452_kernel<<<dim3(NBLK), dim3(256), SMEM_TOTAL, stream>>>(
      x, Whx, Whh, Wph, bh, bp, out);
}

// Round 3
// 2832.795 us; speedup vs baseline: 2.5026x; 1.6395x over previous
//
#include <hip/hip_runtime.h>
#include <hip/hip_bf16.h>
#include <hip/hip_fp8.h>
#include <cstdint>
#include <cstddef>

// VanillaRNN: h_{t+1} = tanh(x_t @ Whx + h_t @ Whh + bh), p = h_T @ Wph + bp
// B=256, T=1024, D=64, H=512, C=10.
//
// R2 vs R1 (R1: 4644us; per-CU MfmaUtil 21% / VALUBusy 32% / ~45% stall at
// 1 wave/SIMD -> ds_read latency + epilogue VALU fully exposed):
//  - 8 waves/block (512 thr), each wave owns 64 cols (4 N-tiles) ->
//    bf16 weights/wave = 48 frags = 192 VGPRs; __launch_bounds__(512,2)
//    -> 2 waves/SIMD: sibling wave's MFMA hides this wave's VALU/LDS latency
//    (m114 pipe overlap). MFMA floor per SIMD unchanged; stalls shrink.
//  - Arithmetic identical to R1 (same 384/192 bf16/fp8 K-split, same scales,
//    same per-accumulator MFMA order) -> absmax should match R1 (~1.34e-3).
// Unchanged: 16 blocks (zero inter-block sync), fp8 weight slice in LDS,
// h ping-pong in LDS (bf16 cols<320, fp8 cols>=320), 1 barrier/step.

#define T_SEQ   1024
#define D_IN    64
#define H_DIM   512
#define NB      16
#define NBLK    16
#define NWAVE   8
#define NTW     4           // N-tiles per wave (64 cols)
#define RKS     12          // bf16 K-steps: k in [0,384)
#define LKS     6           // fp8  K-steps: k in [384,576)
#define APITCH  1040        // bytes per A row: 128 x-bf16 + 640 h-bf16 + 192 fp8 + pad
#define FP8OFF  768
#define HSPLIT  320
#define ABUF_BYTES (2 * NB * APITCH)             // 33280
#define WWAVE_BYTES (LKS * 2 * 1024)             // 12288 per wave
#define WLDS_BYTES (NWAVE * WWAVE_BYTES)         // 98304
#define SMEM_TOTAL (ABUF_BYTES + WLDS_BYTES)     // 131584
#define WSCALE  256.0f
#define HSCALE  128.0f
#define UNSCALE (1.0f / 32768.0f)

typedef __attribute__((ext_vector_type(8))) short  short8;
typedef __attribute__((ext_vector_type(4))) short  short4v;
typedef __attribute__((ext_vector_type(4))) float  f32x4;
typedef __attribute__((ext_vector_type(4))) unsigned int uint4v;

static __device__ __forceinline__ short bf16b(float v) {
  return __builtin_bit_cast(short, __float2bfloat16(v));
}

static __device__ __forceinline__ float fast_tanh(float x) {
  x = fminf(20.f, fmaxf(-20.f, x));
  const float t = __builtin_amdgcn_exp2f(x * 2.885390081777927f); // 2*log2(e)
  return (t - 1.f) * __builtin_amdgcn_rcpf(t + 1.f);
}

static __device__ __forceinline__ unsigned char f32_to_fp8(float v) {
#if defined(__has_builtin) && __has_builtin(__builtin_amdgcn_cvt_pk_fp8_f32)
  const int r = __builtin_amdgcn_cvt_pk_fp8_f32(v, v, 0, false);
  return (unsigned char)(r & 0xff);
#else
  __hip_fp8_e4m3 f(v);
  return (unsigned char)f.__x;
#endif
}

static __device__ __forceinline__ float fp8_to_f32(unsigned char b) {
  __hip_fp8_e4m3 f;
  f.__x = (__hip_fp8_storage_t)b;
  return (float)f;
}

__global__ __launch_bounds__(512, 2)
void VanillaRNN_70025146794452_kernel(
    const float* __restrict__ x,    // [256][1024][64]
    const float* __restrict__ Whx,  // [64][512]
    const float* __restrict__ Whh,  // [512][512]
    const float* __restrict__ Wph,  // [512][10]
    const float* __restrict__ bh,   // [512]
    const float* __restrict__ bp,   // [10]
    float* __restrict__ out)        // [256][10]
{
  const int tid   = threadIdx.x;
  const int lane  = tid & 63;
  const int w     = tid >> 6;       // wave 0..7
  const int n16   = lane & 15;
  const int kq    = lane >> 4;
  const int rbase = blockIdx.x * NB;
  const int cwave = w * 64;         // this wave's 64-column slice

  extern __shared__ char smem[];
  char* Ab  = smem;                                   // [2][NB][APITCH]
  char* Wlw = smem + ABUF_BYTES + w * WWAVE_BYTES;    // this wave's fp8 weights

  // -------- preload: register-resident bf16 B-fragments (k<384), 48 frags ----
  // 16x16x32 B-frag: lane holds B[k0 + kq*8 + j][c0 + n16], j=0..7
  short8 wr[RKS * NTW];
  #pragma unroll
  for (int s = 0; s < RKS; ++s) {
    #pragma unroll
    for (int nt = 0; nt < NTW; ++nt) {
      const int c  = cwave + nt * 16 + n16;
      const int k0 = s * 32 + kq * 8;
      short8 f;
      #pragma unroll
      for (int j = 0; j < 8; ++j) {
        const int k = k0 + j;
        const float* src = (k < D_IN) ? (Whx + (size_t)k * H_DIM + c)
                                      : (Whh + (size_t)(k - D_IN) * H_DIM + c);
        f[j] = bf16b(*src);
      }
      wr[s * NTW + nt] = f;
    }
  }

  // -------- preload: LDS fp8 B-fragments (k in [384,576)), 12 pairs/wave -----
  // pair p = s*2+pp holds nt=2pp (q.x,q.y) and nt=2pp+1 (q.z,q.w) at
  // p*1024 + lane*16.
  for (int s = 0; s < LKS; ++s) {
    for (int pp = 0; pp < 2; ++pp) {
      const int k0 = (RKS + s) * 32 + kq * 8;   // >= 384 -> Whh row >= 320
      unsigned int b[4];
      #pragma unroll
      for (int half = 0; half < 2; ++half) {
        const int c = cwave + (2 * pp + half) * 16 + n16;
        #pragma unroll
        for (int u = 0; u < 2; ++u) {
          unsigned int acc = 0;
          #pragma unroll
          for (int bi = 0; bi < 4; ++bi) {
            const int k = k0 + u * 4 + bi;
            acc |= ((unsigned int)f32_to_fp8(Whh[(size_t)(k - D_IN) * H_DIM + c] * WSCALE))
                   << (8 * bi);
          }
          b[half * 2 + u] = acc;
        }
      }
      uint4v pk; pk.x = b[0]; pk.y = b[1]; pk.z = b[2]; pk.w = b[3];
      *(uint4v*)(Wlw + (size_t)(s * 2 + pp) * 1024 + lane * 16) = pk;
    }
  }

  float bhreg[NTW];
  #pragma unroll
  for (int nt = 0; nt < NTW; ++nt) bhreg[nt] = bh[cwave + nt * 16 + n16];

  // -------- prologue: zero both A buffers, stage x_0 --------------------------
  for (int i = tid; i < ABUF_BYTES / 4; i += 512) ((int*)Ab)[i] = 0;
  const int xr = (tid >> 4) & 15, xc4 = (tid & 15) * 4;   // used by waves 0..3
  if (tid < 256) {
    const f32x4 xv = *(const f32x4*)(x + ((size_t)(rbase + xr) * T_SEQ + 0) * D_IN + xc4);
    short4v s4; s4[0] = bf16b(xv.x); s4[1] = bf16b(xv.y);
    s4[2] = bf16b(xv.z); s4[3] = bf16b(xv.w);
    *(short4v*)(Ab + xr * APITCH + xc4 * 2) = s4;
  }

  f32x4 C[NTW], C2[NTW];

  // -------- main recurrence ---------------------------------------------------
  for (int t = 0; t < T_SEQ; ++t) {
    __syncthreads();
    char* Ac = Ab + (t & 1) * (NB * APITCH);
    char* An = Ab + ((t + 1) & 1) * (NB * APITCH);

    const int t1 = (t + 1 < T_SEQ) ? (t + 1) : (T_SEQ - 1);
    f32x4 xv;
    if (tid < 256)
      xv = *(const f32x4*)(x + ((size_t)(rbase + xr) * T_SEQ + t1) * D_IN + xc4);

    #pragma unroll
    for (int nt = 0; nt < NTW; ++nt) {
      C[nt]  = (f32x4){0.f, 0.f, 0.f, 0.f};
      C2[nt] = (f32x4){0.f, 0.f, 0.f, 0.f};
    }

    // bf16 section: k in [0,384), weights in registers
    #pragma unroll
    for (int s = 0; s < RKS; ++s) {
      const short8 a = *(const short8*)(Ac + n16 * APITCH + s * 64 + kq * 16);
      #pragma unroll
      for (int nt = 0; nt < NTW; ++nt)
        C[nt] = __builtin_amdgcn_mfma_f32_16x16x32_bf16(a, wr[s * NTW + nt], C[nt], 0, 0, 0);
    }

    // fp8 section: k in [384,576), weights in LDS, A slice fp8
    #pragma unroll
    for (int s = 0; s < LKS; ++s) {
      const long long a8 = *(const long long*)(Ac + n16 * APITCH + FP8OFF + s * 32 + kq * 8);
      #pragma unroll
      for (int pp = 0; pp < 2; ++pp) {
        const uint4v q = *(const uint4v*)(Wlw + (size_t)(s * 2 + pp) * 1024 + lane * 16);
        const long long b0 = (long long)(((unsigned long long)q.y << 32) | q.x);
        const long long b1 = (long long)(((unsigned long long)q.w << 32) | q.z);
        C2[2 * pp]     = __builtin_amdgcn_mfma_f32_16x16x32_fp8_fp8(a8, b0, C2[2 * pp],     0, 0, 0);
        C2[2 * pp + 1] = __builtin_amdgcn_mfma_f32_16x16x32_fp8_fp8(a8, b1, C2[2 * pp + 1], 0, 0, 0);
      }
    }

    // stage x_{t+1}
    if (tid < 256) {
      short4v s4; s4[0] = bf16b(xv.x); s4[1] = bf16b(xv.y);
      s4[2] = bf16b(xv.z); s4[3] = bf16b(xv.w);
      *(short4v*)(An + xr * APITCH + xc4 * 2) = s4;
    }

    // epilogue: h = tanh(C + C2*2^-15 + bh); C/D row = kq*4+i, col = n16
    const int row0 = kq * 4;
    #pragma unroll
    for (int nt = 0; nt < NTW; ++nt) {
      const int cbase = cwave + nt * 16;       // wave-uniform
      #pragma unroll
      for (int i = 0; i < 4; ++i) {
        const float v = fast_tanh(fmaf(C2[nt][i], UNSCALE, C[nt][i]) + bhreg[nt]);
        char* dst = An + (row0 + i) * APITCH;
        if (cbase < HSPLIT) {
          *(short*)(dst + 128 + (cbase + n16) * 2) = bf16b(v);
        } else {
          dst[FP8OFF + (cbase + n16 - HSPLIT)] = f32_to_fp8(v * HSCALE);
        }
      }
    }
  }

  __syncthreads();
  // h_T in buffer 0 (T even). Projection: 16 rows x 10 classes per block.
  if (tid < NB * 10) {
    const int r = tid / 10, c = tid % 10;
    const char* row = Ab + r * APITCH;
    float acc = bp[c];
    #pragma unroll 8
    for (int k = 0; k < HSPLIT; ++k) {
      const __hip_bfloat16 hb = __builtin_bit_cast(__hip_bfloat16, *(const short*)(row + 128 + k * 2));
      acc += __bfloat162float(hb) * Wph[k * 10 + c];
    }
    #pragma unroll 8
    for (int k = HSPLIT; k < H_DIM; ++k) {
      acc += fp8_to_f32((unsigned char)row[FP8OFF + (k - HSPLIT)]) * (1.f / HSCALE) * Wph[k * 10 + c];
    }
    out[(size_t)(rbase + r) * 10 + c] = acc;
  }
}

extern "C" void kernel_launch(void* const* d_in, const int* in_sizes, int n_in,
                              void* d_out, int out_size, void* d_ws, size_t ws_size,
                              hipStream_t stream) {
  const float* x   = (const float*)d_in[0];
  const float* Whx = (const float*)d_in[1];
  const float* Whh = (const float*)d_in[2];
  const float* Wph = (const float*)d_in[3];
  const float* bh  = (const float*)d_in[4];
  const float* bp  = (const float*)d_in[5];
  float* out = (float*)d_out;

  (void)hipFuncSetAttribute((const void*)VanillaRNN_70025146794452_kernel,
                            hipFuncAttributeMaxDynamicSharedMemorySize, SMEM_TOTAL);

  VanillaRNN_70025146794452_kernel<<<dim3(NBLK), dim3(512), SMEM_TOTAL, stream>>>(
      x, Whx, Whh, Wph, bh, bp, out);
}

// Round 4
// 1898.625 us; speedup vs baseline: 3.7340x; 1.4920x over previous
//
#include <hip/hip_runtime.h>
#include <hip/hip_bf16.h>
#include <hip/hip_fp8.h>
#include <cstdint>
#include <cstddef>

// VanillaRNN: h_{t+1} = tanh(x_t @ Whx + h_t @ Whh + bh), p = h_T @ Wph + bp
// B=256, T=1024, D=64, H=512, C=10.
//
// R3 vs R2 (R2: 2833us; step=6460cyc vs 2320 MFMA floor; LDS pipe ~1730cyc/step
// incl. 98KB/step fp8-weight RE-reads; tight ds_read->MFMA chains):
//  - U = x@Whx + bh precomputed for ALL t by a parallel kernel into d_ws (f16,
//    swizzled to thread slots). Recurrence K: 576->512, no x staging, C-init=U.
//  - Operand swap: weights are the A-operand, h the B-operand. D is transposed
//    -> each lane holds 4 CONSECUTIVE h columns -> packed b64/b32 epilogue
//    writes. h stored f16 (same MFMA rate as bf16, 8x finer mantissa).
//  - Freed 32 VGPRs (wr 192->160) -> 2 of 6 fp8 weight K-steps live in regs;
//    LDS weight re-reads 12->8 KB/wave/step. LDS ~1330cyc < MFMA 2060cyc.
//  - Fallback (ws too small for U): R2 kernel verbatim.

#define T_SEQ   1024
#define D_IN    64
#define H_DIM   512
#define NB      16
#define NBLK    16
#define NTW     4            // N-tiles (16 cols) per wave; wave owns 64 cols
#define KS_F16  10           // f16 K-steps: h[0,320)
#define KS_REG8 2            // fp8 K-steps with reg weights: h[320,384)
#define KS_LDS8 4            // fp8 K-steps with LDS weights: h[384,512)
#define HSPLIT  320          // h cols >= HSPLIT stored fp8
#define APITCH  848          // bytes per A row: 640 f16 + 192 fp8 + 16 pad
#define FP8OFF  640
#define ABUF_BYTES (2 * NB * APITCH)              // 27136
#define WWAVE_BYTES (KS_LDS8 * 2 * 1024)          // 8192
#define WLDS_BYTES (8 * WWAVE_BYTES)              // 65536
#define SMEM_TOTAL (ABUF_BYTES + WLDS_BYTES)      // 92672
#define WSCALE  256.0f
#define HSCALE  128.0f
#define UNSCALE (1.0f / 32768.0f)
#define U_BYTES ((size_t)256 * 1024 * 512 * 2)    // 268435456 (f16 U)
#define TT      16           // t-tile per precompute block

typedef __attribute__((ext_vector_type(8))) short  short8;
typedef __attribute__((ext_vector_type(4))) short  short4v;
typedef __attribute__((ext_vector_type(4))) float  f32x4;
typedef __attribute__((ext_vector_type(2))) _Float16 h2v;
typedef __attribute__((ext_vector_type(4))) unsigned int uint4v;
typedef __attribute__((ext_vector_type(2))) unsigned int uint2v;

static __device__ __forceinline__ short f16b(float v) {
  return __builtin_bit_cast(short, (_Float16)v);
}
static __device__ __forceinline__ short bf16b(float v) {
  return __builtin_bit_cast(short, __float2bfloat16(v));
}
static __device__ __forceinline__ float f16f(unsigned short u) {
  return (float)__builtin_bit_cast(_Float16, (short)u);
}
static __device__ __forceinline__ unsigned int pk2h(float a, float b) {
#if defined(__has_builtin) && __has_builtin(__builtin_amdgcn_cvt_pkrtz)
  return __builtin_bit_cast(unsigned int, __builtin_amdgcn_cvt_pkrtz(a, b));
#else
  return (unsigned int)(unsigned short)f16b(a) |
         ((unsigned int)(unsigned short)f16b(b) << 16);
#endif
}
static __device__ __forceinline__ float fast_tanh(float x) {
  x = fminf(20.f, fmaxf(-20.f, x));
  const float t = __builtin_amdgcn_exp2f(x * 2.885390081777927f); // 2*log2(e)
  return (t - 1.f) * __builtin_amdgcn_rcpf(t + 1.f);
}
static __device__ __forceinline__ unsigned char f32_to_fp8(float v) {
#if defined(__has_builtin) && __has_builtin(__builtin_amdgcn_cvt_pk_fp8_f32)
  const int r = __builtin_amdgcn_cvt_pk_fp8_f32(v, v, 0, false);
  return (unsigned char)(r & 0xff);
#else
  __hip_fp8_e4m3 f(v);
  return (unsigned char)f.__x;
#endif
}
static __device__ __forceinline__ unsigned int pk4fp8(float a, float b, float c, float d) {
#if defined(__has_builtin) && __has_builtin(__builtin_amdgcn_cvt_pk_fp8_f32)
  int r = __builtin_amdgcn_cvt_pk_fp8_f32(a, b, 0, false);
  r = __builtin_amdgcn_cvt_pk_fp8_f32(c, d, r, true);
  return (unsigned int)r;
#else
  return (unsigned int)f32_to_fp8(a) | ((unsigned int)f32_to_fp8(b) << 8) |
         ((unsigned int)f32_to_fp8(c) << 16) | ((unsigned int)f32_to_fp8(d) << 24);
#endif
}
static __device__ __forceinline__ float fp8_to_f32(unsigned char b) {
  __hip_fp8_e4m3 f;
  f.__x = (__hip_fp8_storage_t)b;
  return (float)f;
}

// ============================ precompute: U = x@Whx + bh =====================
// U slot layout: thread (wg, tid) at step t owns 32 B at slot*32,
// slot = (t*NBLK + wg)*512 + tid. 32B = 4 nt-groups x (2 dwords = 4 f16),
// values z[b=n16][c = wg-wave*64 + nt*16 + kq*4 + i], dword0={i0,i1}, d1={i2,i3}.
__global__ __launch_bounds__(512, 2)
void rnn_u_precompute(const float* __restrict__ x, const float* __restrict__ Whx,
                      const float* __restrict__ bh, char* __restrict__ U)
{
  const int tid  = threadIdx.x;
  const int lane = tid & 63;
  const int w    = tid >> 6;
  const int n16  = lane & 15;
  const int kq   = lane >> 4;
  const int rbase = blockIdx.x * NB;
  const int cwave = w * 64;

  // A-operand frags: Whx^T. lane m=n16 -> col c; holds Whx[k0+kq*8+j][c].
  short8 wa[2][NTW];
  #pragma unroll
  for (int s = 0; s < 2; ++s) {
    #pragma unroll
    for (int nt = 0; nt < NTW; ++nt) {
      const int c = cwave + nt * 16 + n16;
      short8 f;
      #pragma unroll
      for (int j = 0; j < 8; ++j)
        f[j] = f16b(Whx[(size_t)(s * 32 + kq * 8 + j) * H_DIM + c]);
      wa[s][nt] = f;
    }
  }
  f32x4 bb[NTW];
  #pragma unroll
  for (int nt = 0; nt < NTW; ++nt) {
    #pragma unroll
    for (int i = 0; i < 4; ++i) bb[nt][i] = bh[cwave + nt * 16 + kq * 4 + i];
  }

  const int b = rbase + n16;
  for (int tt = 0; tt < TT; ++tt) {
    const int t = blockIdx.y * TT + tt;
    // B-operand frags from x (fp32 -> f16): lane n=n16 -> batch row b.
    short8 xb[2];
    #pragma unroll
    for (int s = 0; s < 2; ++s) {
      const float* px = x + ((size_t)b * T_SEQ + t) * D_IN + s * 32 + kq * 8;
      const f32x4 v0 = *(const f32x4*)px;
      const f32x4 v1 = *(const f32x4*)(px + 4);
      short8 f;
      f[0]=f16b(v0.x); f[1]=f16b(v0.y); f[2]=f16b(v0.z); f[3]=f16b(v0.w);
      f[4]=f16b(v1.x); f[5]=f16b(v1.y); f[6]=f16b(v1.z); f[7]=f16b(v1.w);
      xb[s] = f;
    }
    f32x4 D[NTW];
    #pragma unroll
    for (int nt = 0; nt < NTW; ++nt) {
      D[nt] = bb[nt];
      D[nt] = __builtin_amdgcn_mfma_f32_16x16x32_f16(wa[0][nt], xb[0], D[nt], 0, 0, 0);
      D[nt] = __builtin_amdgcn_mfma_f32_16x16x32_f16(wa[1][nt], xb[1], D[nt], 0, 0, 0);
    }
    uint4v o0, o1;
    o0.x = pk2h(D[0][0], D[0][1]); o0.y = pk2h(D[0][2], D[0][3]);
    o0.z = pk2h(D[1][0], D[1][1]); o0.w = pk2h(D[1][2], D[1][3]);
    o1.x = pk2h(D[2][0], D[2][1]); o1.y = pk2h(D[2][2], D[2][3]);
    o1.z = pk2h(D[3][0], D[3][1]); o1.w = pk2h(D[3][2], D[3][3]);
    char* dst = U + (((size_t)t * NBLK + blockIdx.x) * 512 + tid) * 32;
    *(uint4v*)dst = o0;
    *(uint4v*)(dst + 16) = o1;
  }
}

// ============================ main recurrence ================================
__global__ __launch_bounds__(512, 2)
void VanillaRNN_70025146794452_kernel(
    const float* __restrict__ Whh,  // [512][512]
    const float* __restrict__ Wph,  // [512][10]
    const float* __restrict__ bp,   // [10]
    const char* __restrict__ U,     // precomputed, swizzled f16
    float* __restrict__ out)        // [256][10]
{
  const int tid  = threadIdx.x;
  const int lane = tid & 63;
  const int w    = tid >> 6;
  const int n16  = lane & 15;
  const int kq   = lane >> 4;
  const int rbase = blockIdx.x * NB;
  const int cwave = w * 64;

  extern __shared__ char smem[];
  char* Ab  = smem;                                  // [2][NB][APITCH]
  char* Wlw = smem + ABUF_BYTES + w * WWAVE_BYTES;   // this wave's fp8 weights

  // -------- preload: f16 weight A-frags (h-k in [0,320)), 40 frags = 160 regs
  // A-frag: lane m=n16 -> col c; holds Whh[k0+kq*8+j][c], j=0..7.
  short8 wr[KS_F16][NTW];
  #pragma unroll
  for (int s = 0; s < KS_F16; ++s) {
    #pragma unroll
    for (int nt = 0; nt < NTW; ++nt) {
      const int c = cwave + nt * 16 + n16;
      short8 f;
      #pragma unroll
      for (int j = 0; j < 8; ++j)
        f[j] = f16b(Whh[(size_t)(s * 32 + kq * 8 + j) * H_DIM + c]);
      wr[s][nt] = f;
    }
  }
  // -------- preload: reg-resident fp8 weight A-frags (h-k in [320,384))
  long long wf8[KS_REG8][NTW];
  #pragma unroll
  for (int s = 0; s < KS_REG8; ++s) {
    #pragma unroll
    for (int nt = 0; nt < NTW; ++nt) {
      const int c  = cwave + nt * 16 + n16;
      const int k0 = (KS_F16 + s) * 32 + kq * 8;
      unsigned int lo = 0, hi = 0;
      #pragma unroll
      for (int bi = 0; bi < 4; ++bi) {
        lo |= ((unsigned int)f32_to_fp8(Whh[(size_t)(k0 + bi) * H_DIM + c] * WSCALE)) << (8 * bi);
        hi |= ((unsigned int)f32_to_fp8(Whh[(size_t)(k0 + 4 + bi) * H_DIM + c] * WSCALE)) << (8 * bi);
      }
      wf8[s][nt] = (long long)(((unsigned long long)hi << 32) | lo);
    }
  }
  // -------- preload: LDS fp8 weight A-frags (h-k in [384,512))
  // chunk = sl*2+half holds tiles nt=2half (q.x,q.y), nt=2half+1 (q.z,q.w).
  for (int sl = 0; sl < KS_LDS8; ++sl) {
    for (int half = 0; half < 2; ++half) {
      const int k0 = (KS_F16 + KS_REG8 + sl) * 32 + kq * 8;
      unsigned int bqq[4];
      #pragma unroll
      for (int hh = 0; hh < 2; ++hh) {
        const int c = cwave + (2 * half + hh) * 16 + n16;
        #pragma unroll
        for (int u = 0; u < 2; ++u) {
          unsigned int acc = 0;
          #pragma unroll
          for (int bi = 0; bi < 4; ++bi)
            acc |= ((unsigned int)f32_to_fp8(Whh[(size_t)(k0 + u * 4 + bi) * H_DIM + c] * WSCALE)) << (8 * bi);
          bqq[hh * 2 + u] = acc;
        }
      }
      uint4v pk; pk.x = bqq[0]; pk.y = bqq[1]; pk.z = bqq[2]; pk.w = bqq[3];
      *(uint4v*)(Wlw + (size_t)(sl * 2 + half) * 1024 + lane * 16) = pk;
    }
  }

  // -------- prologue: zero both A buffers (h_0 = 0), prefetch U(t=0)
  for (int i = tid; i < ABUF_BYTES / 4; i += 512) ((int*)Ab)[i] = 0;
  uint4v Upf0, Upf1;
  {
    const char* up = U + (((size_t)0 * NBLK + blockIdx.x) * 512 + tid) * 32;
    Upf0 = *(const uint4v*)up;
    Upf1 = *(const uint4v*)(up + 16);
  }

  f32x4 C[NTW], C2[NTW];

  // -------- main recurrence
  for (int t = 0; t < T_SEQ; ++t) {
    __syncthreads();
    char* Ac = Ab + (t & 1) * (NB * APITCH);
    char* An = Ab + ((t + 1) & 1) * (NB * APITCH);

    // C-init from prefetched U (z_x + bh), then prefetch t+1.
    C[0][0]=f16f(Upf0.x&0xffff); C[0][1]=f16f(Upf0.x>>16);
    C[0][2]=f16f(Upf0.y&0xffff); C[0][3]=f16f(Upf0.y>>16);
    C[1][0]=f16f(Upf0.z&0xffff); C[1][1]=f16f(Upf0.z>>16);
    C[1][2]=f16f(Upf0.w&0xffff); C[1][3]=f16f(Upf0.w>>16);
    C[2][0]=f16f(Upf1.x&0xffff); C[2][1]=f16f(Upf1.x>>16);
    C[2][2]=f16f(Upf1.y&0xffff); C[2][3]=f16f(Upf1.y>>16);
    C[3][0]=f16f(Upf1.z&0xffff); C[3][1]=f16f(Upf1.z>>16);
    C[3][2]=f16f(Upf1.w&0xffff); C[3][3]=f16f(Upf1.w>>16);
    #pragma unroll
    for (int nt = 0; nt < NTW; ++nt) C2[nt] = (f32x4){0.f, 0.f, 0.f, 0.f};
    {
      const int t1 = (t + 1 < T_SEQ) ? (t + 1) : (T_SEQ - 1);
      const char* up = U + (((size_t)t1 * NBLK + blockIdx.x) * 512 + tid) * 32;
      Upf0 = *(const uint4v*)up;
      Upf1 = *(const uint4v*)(up + 16);
    }

    // f16 section: h-k in [0,320). B-frag: lane n=n16 -> batch row; software
    // prefetch of next frag keeps ds_read ahead of the dependent MFMAs.
    short8 hb = *(const short8*)(Ac + n16 * APITCH + 0 * 64 + kq * 16);
    #pragma unroll
    for (int s = 0; s < KS_F16; ++s) {
      const short8 a = hb;
      if (s + 1 < KS_F16)
        hb = *(const short8*)(Ac + n16 * APITCH + (s + 1) * 64 + kq * 16);
      #pragma unroll
      for (int nt = 0; nt < NTW; ++nt)
        C[nt] = __builtin_amdgcn_mfma_f32_16x16x32_f16(wr[s][nt], a, C[nt], 0, 0, 0);
    }
    // fp8 reg-weight section: h-k in [320,384)
    #pragma unroll
    for (int s = 0; s < KS_REG8; ++s) {
      const long long h8 = *(const long long*)(Ac + n16 * APITCH + FP8OFF + s * 32 + kq * 8);
      #pragma unroll
      for (int nt = 0; nt < NTW; ++nt)
        C2[nt] = __builtin_amdgcn_mfma_f32_16x16x32_fp8_fp8(wf8[s][nt], h8, C2[nt], 0, 0, 0);
    }
    // fp8 LDS-weight section: h-k in [384,512)
    #pragma unroll
    for (int sl = 0; sl < KS_LDS8; ++sl) {
      const long long h8 = *(const long long*)(Ac + n16 * APITCH + FP8OFF + (KS_REG8 + sl) * 32 + kq * 8);
      const uint4v q0 = *(const uint4v*)(Wlw + (size_t)(sl * 2 + 0) * 1024 + lane * 16);
      const uint4v q1 = *(const uint4v*)(Wlw + (size_t)(sl * 2 + 1) * 1024 + lane * 16);
      const long long w0 = (long long)(((unsigned long long)q0.y << 32) | q0.x);
      const long long w1 = (long long)(((unsigned long long)q0.w << 32) | q0.z);
      const long long w2 = (long long)(((unsigned long long)q1.y << 32) | q1.x);
      const long long w3 = (long long)(((unsigned long long)q1.w << 32) | q1.z);
      C2[0] = __builtin_amdgcn_mfma_f32_16x16x32_fp8_fp8(w0, h8, C2[0], 0, 0, 0);
      C2[1] = __builtin_amdgcn_mfma_f32_16x16x32_fp8_fp8(w1, h8, C2[1], 0, 0, 0);
      C2[2] = __builtin_amdgcn_mfma_f32_16x16x32_fp8_fp8(w2, h8, C2[2], 0, 0, 0);
      C2[3] = __builtin_amdgcn_mfma_f32_16x16x32_fp8_fp8(w3, h8, C2[3], 0, 0, 0);
    }

    // epilogue: D is TRANSPOSED -> lane n16 = batch row, reg i = col kq*4+i.
    // 4 consecutive cols per (nt): packed b64 (f16) or b32 (fp8) writes.
    char* drow = An + n16 * APITCH;
    if (cwave < HSPLIT) {            // waves 0..4: f16 region
      #pragma unroll
      for (int nt = 0; nt < NTW; ++nt) {
        const int c0 = cwave + nt * 16 + kq * 4;
        float v0 = fast_tanh(fmaf(C2[nt][0], UNSCALE, C[nt][0]));
        float v1 = fast_tanh(fmaf(C2[nt][1], UNSCALE, C[nt][1]));
        float v2 = fast_tanh(fmaf(C2[nt][2], UNSCALE, C[nt][2]));
        float v3 = fast_tanh(fmaf(C2[nt][3], UNSCALE, C[nt][3]));
        uint2v o; o.x = pk2h(v0, v1); o.y = pk2h(v2, v3);
        *(uint2v*)(drow + c0 * 2) = o;
      }
    } else {                          // waves 5..7: fp8 region
      #pragma unroll
      for (int nt = 0; nt < NTW; ++nt) {
        const int c0 = cwave + nt * 16 + kq * 4;
        float v0 = fast_tanh(fmaf(C2[nt][0], UNSCALE, C[nt][0]));
        float v1 = fast_tanh(fmaf(C2[nt][1], UNSCALE, C[nt][1]));
        float v2 = fast_tanh(fmaf(C2[nt][2], UNSCALE, C[nt][2]));
        float v3 = fast_tanh(fmaf(C2[nt][3], UNSCALE, C[nt][3]));
        *(unsigned int*)(drow + FP8OFF + (c0 - HSPLIT)) =
            pk4fp8(v0 * HSCALE, v1 * HSCALE, v2 * HSCALE, v3 * HSCALE);
      }
    }
  }

  __syncthreads();
  // h_T in buffer 0 (T even). Projection: 16 rows x 10 classes per block.
  if (tid < NB * 10) {
    const int r = tid / 10, c = tid % 10;
    const char* row = Ab + r * APITCH;
    float acc = bp[c];
    #pragma unroll 8
    for (int k = 0; k < HSPLIT; ++k)
      acc += f16f(*(const unsigned short*)(row + k * 2)) * Wph[k * 10 + c];
    #pragma unroll 8
    for (int k = HSPLIT; k < H_DIM; ++k)
      acc += fp8_to_f32((unsigned char)row[FP8OFF + (k - HSPLIT)]) * (1.f / HSCALE) * Wph[k * 10 + c];
    out[(size_t)(rbase + r) * 10 + c] = acc;
  }
}

// ============================ fallback (R2 verbatim) =========================
// Used only when ws_size cannot hold U. 2833us measured.
#define FB_APITCH  1040
#define FB_FP8OFF  768
#define FB_ABUF    (2 * NB * FB_APITCH)
#define FB_WWAVE   (6 * 2 * 1024)
#define FB_SMEM    (FB_ABUF + 8 * FB_WWAVE)       // 131584

__global__ __launch_bounds__(512, 2)
void rnn_fallback_kernel(
    const float* __restrict__ x, const float* __restrict__ Whx,
    const float* __restrict__ Whh, const float* __restrict__ Wph,
    const float* __restrict__ bh, const float* __restrict__ bp,
    float* __restrict__ out)
{
  const int tid = threadIdx.x, lane = tid & 63, w = tid >> 6;
  const int n16 = lane & 15, kq = lane >> 4;
  const int rbase = blockIdx.x * NB, cwave = w * 64;
  extern __shared__ char smem[];
  char* Ab  = smem;
  char* Wlw = smem + FB_ABUF + w * FB_WWAVE;

  short8 wr[12 * 4];
  #pragma unroll
  for (int s = 0; s < 12; ++s)
    #pragma unroll
    for (int nt = 0; nt < 4; ++nt) {
      const int c = cwave + nt * 16 + n16, k0 = s * 32 + kq * 8;
      short8 f;
      #pragma unroll
      for (int j = 0; j < 8; ++j) {
        const int k = k0 + j;
        const float* src = (k < D_IN) ? (Whx + (size_t)k * H_DIM + c)
                                      : (Whh + (size_t)(k - D_IN) * H_DIM + c);
        f[j] = bf16b(*src);
      }
      wr[s * 4 + nt] = f;
    }
  for (int s = 0; s < 6; ++s)
    for (int pp = 0; pp < 2; ++pp) {
      const int k0 = (12 + s) * 32 + kq * 8;
      unsigned int bq[4];
      #pragma unroll
      for (int half = 0; half < 2; ++half) {
        const int c = cwave + (2 * pp + half) * 16 + n16;
        #pragma unroll
        for (int u = 0; u < 2; ++u) {
          unsigned int acc = 0;
          #pragma unroll
          for (int bi = 0; bi < 4; ++bi)
            acc |= ((unsigned int)f32_to_fp8(Whh[(size_t)(k0 + u * 4 + bi - D_IN) * H_DIM + c] * WSCALE)) << (8 * bi);
          bq[half * 2 + u] = acc;
        }
      }
      uint4v pk; pk.x = bq[0]; pk.y = bq[1]; pk.z = bq[2]; pk.w = bq[3];
      *(uint4v*)(Wlw + (size_t)(s * 2 + pp) * 1024 + lane * 16) = pk;
    }
  float bhreg[4];
  #pragma unroll
  for (int nt = 0; nt < 4; ++nt) bhreg[nt] = bh[cwave + nt * 16 + n16];
  for (int i = tid; i < FB_ABUF / 4; i += 512) ((int*)Ab)[i] = 0;
  const int xr = (tid >> 4) & 15, xc4 = (tid & 15) * 4;
  if (tid < 256) {
    const f32x4 xv = *(const f32x4*)(x + ((size_t)(rbase + xr) * T_SEQ) * D_IN + xc4);
    short4v s4; s4[0]=bf16b(xv.x); s4[1]=bf16b(xv.y); s4[2]=bf16b(xv.z); s4[3]=bf16b(xv.w);
    *(short4v*)(Ab + xr * FB_APITCH + xc4 * 2) = s4;
  }
  f32x4 C[4], C2[4];
  for (int t = 0; t < T_SEQ; ++t) {
    __syncthreads();
    char* Ac = Ab + (t & 1) * (NB * FB_APITCH);
    char* An = Ab + ((t + 1) & 1) * (NB * FB_APITCH);
    const int t1 = (t + 1 < T_SEQ) ? (t + 1) : (T_SEQ - 1);
    f32x4 xv;
    if (tid < 256)
      xv = *(const f32x4*)(x + ((size_t)(rbase + xr) * T_SEQ + t1) * D_IN + xc4);
    #pragma unroll
    for (int nt = 0; nt < 4; ++nt) {
      C[nt] = (f32x4){0.f,0.f,0.f,0.f}; C2[nt] = (f32x4){0.f,0.f,0.f,0.f};
    }
    #pragma unroll
    for (int s = 0; s < 12; ++s) {
      const short8 a = *(const short8*)(Ac + n16 * FB_APITCH + s * 64 + kq * 16);
      #pragma unroll
      for (int nt = 0; nt < 4; ++nt)
        C[nt] = __builtin_amdgcn_mfma_f32_16x16x32_bf16(a, wr[s * 4 + nt], C[nt], 0, 0, 0);
    }
    #pragma unroll
    for (int s = 0; s < 6; ++s) {
      const long long a8 = *(const long long*)(Ac + n16 * FB_APITCH + FB_FP8OFF + s * 32 + kq * 8);
      #pragma unroll
      for (int pp = 0; pp < 2; ++pp) {
        const uint4v q = *(const uint4v*)(Wlw + (size_t)(s * 2 + pp) * 1024 + lane * 16);
        const long long b0 = (long long)(((unsigned long long)q.y << 32) | q.x);
        const long long b1 = (long long)(((unsigned long long)q.w << 32) | q.z);
        C2[2*pp]   = __builtin_amdgcn_mfma_f32_16x16x32_fp8_fp8(a8, b0, C2[2*pp],   0, 0, 0);
        C2[2*pp+1] = __builtin_amdgcn_mfma_f32_16x16x32_fp8_fp8(a8, b1, C2[2*pp+1], 0, 0, 0);
      }
    }
    if (tid < 256) {
      short4v s4; s4[0]=bf16b(xv.x); s4[1]=bf16b(xv.y); s4[2]=bf16b(xv.z); s4[3]=bf16b(xv.w);
      *(short4v*)(An + xr * FB_APITCH + xc4 * 2) = s4;
    }
    const int row0 = kq * 4;
    #pragma unroll
    for (int nt = 0; nt < 4; ++nt) {
      const int cbase = cwave + nt * 16;
      #pragma unroll
      for (int i = 0; i < 4; ++i) {
        const float v = fast_tanh(fmaf(C2[nt][i], UNSCALE, C[nt][i]) + bhreg[nt]);
        char* dst = An + (row0 + i) * FB_APITCH;
        if (cbase < 320) *(short*)(dst + 128 + (cbase + n16) * 2) = bf16b(v);
        else dst[FB_FP8OFF + (cbase + n16 - 320)] = f32_to_fp8(v * HSCALE);
      }
    }
  }
  __syncthreads();
  if (tid < NB * 10) {
    const int r = tid / 10, c = tid % 10;
    const char* row = Ab + r * FB_APITCH;
    float acc = bp[c];
    #pragma unroll 8
    for (int k = 0; k < 320; ++k) {
      const __hip_bfloat16 hb = __builtin_bit_cast(__hip_bfloat16, *(const short*)(row + 128 + k * 2));
      acc += __bfloat162float(hb) * Wph[k * 10 + c];
    }
    #pragma unroll 8
    for (int k = 320; k < H_DIM; ++k)
      acc += fp8_to_f32((unsigned char)row[FB_FP8OFF + (k - 320)]) * (1.f / HSCALE) * Wph[k * 10 + c];
    out[(size_t)(rbase + r) * 10 + c] = acc;
  }
}

extern "C" void kernel_launch(void* const* d_in, const int* in_sizes, int n_in,
                              void* d_out, int out_size, void* d_ws, size_t ws_size,
                              hipStream_t stream) {
  const float* x   = (const float*)d_in[0];
  const float* Whx = (const float*)d_in[1];
  const float* Whh = (const float*)d_in[2];
  const float* Wph = (const float*)d_in[3];
  const float* bh  = (const float*)d_in[4];
  const float* bp  = (const float*)d_in[5];
  float* out = (float*)d_out;

  if (ws_size >= U_BYTES) {
    char* U = (char*)d_ws;
    (void)hipFuncSetAttribute((const void*)VanillaRNN_70025146794452_kernel,
                              hipFuncAttributeMaxDynamicSharedMemorySize, SMEM_TOTAL);
    rnn_u_precompute<<<dim3(NBLK, T_SEQ / TT), dim3(512), 0, stream>>>(x, Whx, bh, U);
    VanillaRNN_70025146794452_kernel<<<dim3(NBLK), dim3(512), SMEM_TOTAL, stream>>>(
        Whh, Wph, bp, U, out);
  } else {
    (void)hipFuncSetAttribute((const void*)rnn_fallback_kernel,
                              hipFuncAttributeMaxDynamicSharedMemorySize, FB_SMEM);
    rnn_fallback_kernel<<<dim3(NBLK), dim3(512), FB_SMEM, stream>>>(
        x, Whx, Whh, Wph, bh, bp, out);
  }
}